// Round 12
// baseline (462.463 us; speedup 1.0000x reference)
//
#include <hip/hip_runtime.h>
#include <hip/hip_bf16.h>
#include <stdint.h>

// ---------- types / helpers ----------
typedef __attribute__((ext_vector_type(8))) short short8;   // 8 fp16 (MFMA A/B frag)
typedef __attribute__((ext_vector_type(4))) float f32x4;    // MFMA C/D frag
typedef __attribute__((ext_vector_type(2))) float f32x2;
typedef __attribute__((ext_vector_type(4))) unsigned int u32x4;  // nontemporal-capable 16B
typedef __attribute__((ext_vector_type(2))) _Float16 half2_t;

__device__ __forceinline__ uint32_t pack2(float a, float b) {
    auto r = __builtin_amdgcn_cvt_pkrtz(a, b);              // v_cvt_pkrtz_f16_f32
    return __builtin_bit_cast(uint32_t, r);
}
__device__ __forceinline__ uint16_t f2h(float x) {
    auto r = __builtin_amdgcn_cvt_pkrtz(x, 0.0f);
    return (uint16_t)(__builtin_bit_cast(uint32_t, r) & 0xffffu);
}
__device__ __forceinline__ f32x4 mfma_fp8(uint2 a, uint2 b, f32x4 c) {
    return __builtin_amdgcn_mfma_f32_16x16x32_fp8_fp8(
        __builtin_bit_cast(long long, a), __builtin_bit_cast(long long, b), c, 0, 0, 0);
}

// ---- wave run-aggregation for LDS atomics (sorted dst -> same-address RMW fix) ----
// All 64 lanes must execute these. Invalid lanes pass b = -1 (contiguous at wave tail).
__device__ __forceinline__ void agg_hist_add(int b, int lane, int* lcnt) {
    int prev = __shfl_up(b, 1);
    bool head = (lane == 0) || (b != prev);
    unsigned long long heads = __ballot(head);
    unsigned long long mask_le = ((1ull << lane) << 1) - 1ull;   // bits 0..lane (lane=63 -> ~0)
    unsigned long long g = heads & ~mask_le;                     // heads strictly after lane
    int nexthead = g ? (int)__builtin_ctzll(g) : 64;
    if (head && b >= 0) atomicAdd(&lcnt[b], nexthead - lane);    // one RMW per run
}
__device__ __forceinline__ int agg_slot(int b, int lane, int* cnt) {
    int prev = __shfl_up(b, 1);
    bool head = (lane == 0) || (b != prev);
    unsigned long long heads = __ballot(head);
    unsigned long long mask_le = ((1ull << lane) << 1) - 1ull;
    unsigned long long m = heads & mask_le;                      // nonzero: lane0 is a head
    int myhead = 63 - (int)__builtin_clzll(m);
    unsigned long long g = heads & ~mask_le;
    int nexthead = g ? (int)__builtin_ctzll(g) : 64;
    int base = 0;
    if (lane == myhead && b >= 0) base = atomicAdd(&cnt[b], nexthead - lane);
    base = __shfl(base, myhead);
    return base + (lane - myhead);   // caller uses only on valid lanes
}

#define DIM 128
// CSR bucket sort: 128 nodes per bucket (bucket = dst >> 7). Works for N <= 131072.
#define BKT_SHIFT 7
#define BKT_NODES 128
#define MAX_BKT 1024
#define BIN_TILE 8192   // 196 blocks at E=1.6M: TLP for the latency-bound hist/scatter
#define CSR_CAP 3072   // max edges per bucket staged in LDS (mean ~2046, std ~45)
#define LDS_W_STRIDE 136   // 128 + 8 halves: breaks 16-way bank conflict on ds_read_b128
#define NW_BLK 16      // weight-convert role blocks

// ---------- prep: bucket histogram (+inline last-block scan) + weight convert + tangent ----------
__global__ __launch_bounds__(256) void prep_kernel(
    const int* __restrict__ dst, int* __restrict__ bucket_cnt, int* __restrict__ done_cnt,
    int* __restrict__ bstart, int* __restrict__ bcursor,
    int E, int nbuckets, int nbin,
    const float* __restrict__ Wq, const float* __restrict__ Wk, const float* __restrict__ Wv,
    uint16_t* __restrict__ w_h, int wtotal,
    const float* __restrict__ x, uint16_t* __restrict__ t, const float* __restrict__ curv,
    int N) {
    __shared__ int lcnt[MAX_BKT];
    __shared__ int is_last;
    int bx = blockIdx.x;
    int tid = threadIdx.x;
    if (bx < nbin) {
        // --- bucket histogram role (wave-aggregated LDS atomics) ---
        for (int i = tid; i < nbuckets; i += 256) lcnt[i] = 0;
        __syncthreads();
        int base = bx * BIN_TILE;
        int end = min(base + BIN_TILE, E);
        int lane = tid & 63;
        for (int e0 = base; e0 < end; e0 += 256) {
            int e = e0 + tid;
            int b = (e < end) ? (dst[e] >> BKT_SHIFT) : -1;
            agg_hist_add(b, lane, lcnt);
        }
        __syncthreads();
        for (int i = tid; i < nbuckets; i += 256)
            if (lcnt[i]) atomicAdd(&bucket_cnt[i], lcnt[i]);
        // --- last histogram block performs the exclusive scan inline (was bscan_kernel) ---
        if (tid == 0) {
            __threadfence();                               // release our bucket_cnt adds
            int d = atomicAdd(done_cnt, 1);
            is_last = (d == nbin - 1);
        }
        __syncthreads();
        if (is_last) {
            __threadfence();                               // acquire other blocks' adds
            int v4[4];
            #pragma unroll
            for (int c = 0; c < 4; c++) {
                int idx = c * 256 + tid;
                v4[c] = (idx < nbuckets)
                    ? __hip_atomic_load(&bucket_cnt[idx], __ATOMIC_RELAXED, __HIP_MEMORY_SCOPE_AGENT)
                    : 0;
            }
            int run = 0;
            #pragma unroll
            for (int c = 0; c < 4; c++) {
                lcnt[tid] = v4[c]; __syncthreads();
                for (int off = 1; off < 256; off <<= 1) {
                    int tv = (tid >= off) ? lcnt[tid - off] : 0;
                    __syncthreads();
                    lcnt[tid] += tv;
                    __syncthreads();
                }
                int ex = run + lcnt[tid] - v4[c];
                int idx = c * 256 + tid;
                if (idx < nbuckets) { bstart[idx] = ex; bcursor[idx] = ex; }
                run += lcnt[255];
                __syncthreads();
            }
            if (tid == 0) bstart[nbuckets] = E;
        }
    } else if (bx < nbin + NW_BLK) {
        // --- weight conversion role: [l][mat][out_col][k] fp32 -> fp16 ---
        int per_l = 3 * DIM * DIM;
        for (int i = (bx - nbin) * 256 + tid; i < wtotal; i += 256 * NW_BLK) {
            int l = i / per_l;
            int rem = i % per_l;
            int mat = rem / (DIM * DIM);
            int idx = rem % (DIM * DIM);
            const float* s = (mat == 0) ? Wq : (mat == 1) ? Wk : Wv;
            w_h[i] = f2h(s[l * DIM * DIM + idx]);
        }
    } else {
        // --- tangent role: 32 nodes/block, 8 lanes/node, 64B per lane ---
        // t = (2/sc)*atanh(sc*||x||)*x/||x||; atanh via one v_log_f32.
        int n = (bx - nbin - NW_BLK) * 32 + (tid >> 3);
        if (n >= N) return;
        int ln8 = tid & 7;
        const float4* xp = (const float4*)(x + (size_t)n * DIM) + ln8 * 4;
        float4 a0 = xp[0], a1 = xp[1], a2 = xp[2], a3 = xp[3];
        float ss = a0.x * a0.x + a0.y * a0.y + a0.z * a0.z + a0.w * a0.w
                 + a1.x * a1.x + a1.y * a1.y + a1.z * a1.z + a1.w * a1.w
                 + a2.x * a2.x + a2.y * a2.y + a2.z * a2.z + a2.w * a2.w
                 + a3.x * a3.x + a3.y * a3.y + a3.z * a3.z + a3.w * a3.w;
        #pragma unroll
        for (int off = 4; off >= 1; off >>= 1) ss += __shfl_xor(ss, off);
        float c = curv[0];
        float sc = sqrtf(c);
        float r = sqrtf(ss);
        float z = sc * r;
        float f = (r > 1e-30f) ? __logf((1.0f + z) / (1.0f - z)) / (sc * r) : 2.0f;
        uint4 o0, o1;
        o0.x = pack2(f * a0.x, f * a0.y); o0.y = pack2(f * a0.z, f * a0.w);
        o0.z = pack2(f * a1.x, f * a1.y); o0.w = pack2(f * a1.z, f * a1.w);
        o1.x = pack2(f * a2.x, f * a2.y); o1.y = pack2(f * a2.z, f * a2.w);
        o1.z = pack2(f * a3.x, f * a3.y); o1.w = pack2(f * a3.z, f * a3.w);
        uint4* tp = (uint4*)(t + (size_t)n * DIM) + ln8 * 2;
        tp[0] = o0; tp[1] = o1;
    }
}

// ---------- shared gemm body (used by combo + standalone kernels) ----------
// mat 0: q fp8 e4m3 + bias (QK dot runs on fp8 MFMA in attn). mat 1: k fp8 + bias.
// mat 2: v fp16 + bias.
__device__ __forceinline__ void qkv_gemm_body(
    const uint16_t* __restrict__ t, const uint16_t* __restrict__ w,
    const float* __restrict__ bq, const float* __restrict__ bk, const float* __restrict__ bv,
    uint8_t* __restrict__ q8out, uint8_t* __restrict__ k8out, uint16_t* __restrict__ vout,
    int N, int mat, int tile, uint16_t* lw) {
    const uint16_t* wm = w + (size_t)mat * DIM * DIM;
    // stage W: each thread copies half a row (64 halves = 8 x uint4)
    {
        int r = threadIdx.x >> 1, hf = (threadIdx.x & 1) * 64;
        const uint4* srcp = (const uint4*)(wm + r * DIM + hf);
        uint4* dstp = (uint4*)(lw + r * LDS_W_STRIDE + hf);
        #pragma unroll
        for (int i = 0; i < 8; i++) dstp[i] = srcp[i];
    }
    __syncthreads();
    int wave = threadIdx.x >> 6, lane = threadIdx.x & 63;
    int sub = lane & 15, quad = lane >> 4;
    int node0 = tile * 256 + wave * 64;
    const float* bias = (mat == 0) ? bq : (mat == 1) ? bk : bv;
    f32x4 acc[8][4] = {};
    #pragma unroll
    for (int k0 = 0; k0 < DIM; k0 += 32) {
        short8 b[4];
        #pragma unroll
        for (int g = 0; g < 4; g++) {
            int node = node0 + g * 16 + sub;
            int nodec = (node < N) ? node : (N - 1);
            b[g] = *(const short8*)(t + (size_t)nodec * DIM + k0 + quad * 8);
        }
        short8 a[8];
        #pragma unroll
        for (int tl = 0; tl < 8; tl++)
            a[tl] = *(const short8*)(lw + (tl * 16 + sub) * LDS_W_STRIDE + k0 + quad * 8);
        #pragma unroll
        for (int tl = 0; tl < 8; tl++)
            #pragma unroll
            for (int g = 0; g < 4; g++)
                acc[tl][g] = __builtin_amdgcn_mfma_f32_16x16x32_f16(a[tl], b[g], acc[tl][g], 0, 0, 0);
    }
    #pragma unroll
    for (int g = 0; g < 4; g++) {
        int node = node0 + g * 16 + sub;
        if (node >= N) continue;
        if (mat != 2) {
            uint8_t* outp = (mat == 0) ? q8out : k8out;
            #pragma unroll
            for (int tl = 0; tl < 8; tl++) {
                float4 bs = *(const float4*)(bias + tl * 16 + quad * 4);
                int pk = 0;
                pk = __builtin_amdgcn_cvt_pk_fp8_f32(acc[tl][g][0] + bs.x, acc[tl][g][1] + bs.y, pk, false);
                pk = __builtin_amdgcn_cvt_pk_fp8_f32(acc[tl][g][2] + bs.z, acc[tl][g][3] + bs.w, pk, true);
                *(uint32_t*)(outp + (size_t)node * DIM + tl * 16 + quad * 4) = (uint32_t)pk;
            }
        } else {
            #pragma unroll
            for (int tl = 0; tl < 8; tl++) {
                float4 bs = *(const float4*)(bias + tl * 16 + quad * 4);
                uint2 pk;
                pk.x = pack2(acc[tl][g][0] + bs.x, acc[tl][g][1] + bs.y);
                pk.y = pack2(acc[tl][g][2] + bs.z, acc[tl][g][3] + bs.w);
                *(uint2*)(vout + (size_t)node * DIM + tl * 16 + quad * 4) = pk;
            }
        }
    }
}

// ---------- combo: two-phase bin (role) + layer-0 QKV gemm (role), one dispatch ----------
__global__ __launch_bounds__(256) void bin_gemm_kernel(
    const int* __restrict__ src, const int* __restrict__ dst,
    int* __restrict__ bcursor, int2* __restrict__ pair_buf, int E, int nbuckets, int nbin,
    const uint16_t* __restrict__ t, const uint16_t* __restrict__ w,
    const float* __restrict__ bq, const float* __restrict__ bk, const float* __restrict__ bv,
    uint8_t* __restrict__ q8out, uint8_t* __restrict__ k8out, uint16_t* __restrict__ vout,
    int N, int ntiles) {
    __shared__ uint16_t lw[DIM * LDS_W_STRIDE];
    int bx = blockIdx.x;
    if (bx < nbin) {
        // --- bin role: two-phase LDS scatter (round-9 proven form) ---
        int* lcnt = (int*)lw;                        // reuse gemm LDS
        int* lbase = lcnt + MAX_BKT;
        int lane = threadIdx.x & 63;
        for (int i = threadIdx.x; i < nbuckets; i += 256) lcnt[i] = 0;
        __syncthreads();
        int base = bx * BIN_TILE;
        int end = min(base + BIN_TILE, E);
        for (int e0 = base; e0 < end; e0 += 256) {
            int e = e0 + threadIdx.x;
            int b = (e < end) ? (dst[e] >> BKT_SHIFT) : -1;
            agg_hist_add(b, lane, lcnt);
        }
        __syncthreads();
        for (int i = threadIdx.x; i < nbuckets; i += 256) {
            int c = lcnt[i];
            lbase[i] = c ? atomicAdd(&bcursor[i], c) : 0;
        }
        __syncthreads();
        for (int i = threadIdx.x; i < nbuckets; i += 256) lcnt[i] = 0;   // reuse as cursor
        __syncthreads();
        for (int e0 = base; e0 < end; e0 += 256) {
            int e = e0 + threadIdx.x;
            bool valid = (e < end);
            int d = valid ? dst[e] : 0;
            int b = valid ? (d >> BKT_SHIFT) : -1;
            int slot = agg_slot(b, lane, lcnt);
            if (valid) pair_buf[(size_t)lbase[b] + slot] = make_int2(src[e], d);
        }
    } else {
        int id = bx - nbin;
        int mat = id / ntiles, tile = id % ntiles;   // all tiles of mat 0 first: t L3-reuse
        qkv_gemm_body(t, w, bq, bk, bv, q8out, k8out, vout, N, mat, tile, lw);
    }
}

// ---------- standalone QKV gemm (layers >= 1) ----------
__global__ __launch_bounds__(256) void qkv_gemm_kernel(
    const uint16_t* __restrict__ t, const uint16_t* __restrict__ w,
    const float* __restrict__ bq, const float* __restrict__ bk, const float* __restrict__ bv,
    uint8_t* __restrict__ q8out, uint8_t* __restrict__ k8out, uint16_t* __restrict__ vout,
    int N) {
    __shared__ uint16_t lw[DIM * LDS_W_STRIDE];
    qkv_gemm_body(t, w, bq, bk, bv, q8out, k8out, vout, N, blockIdx.y, blockIdx.x, lw);
}

// ---------- CSR build: per-bucket local sort in LDS -> row_start + esrc ----------
__global__ __launch_bounds__(256) void csr_kernel(const int2* __restrict__ pair_buf,
                                                  const int* __restrict__ bstart,
                                                  int* __restrict__ row_start,
                                                  int* __restrict__ esrc,
                                                  int N, int E) {
    __shared__ int cnt[BKT_NODES], incl[BKT_NODES], cur[BKT_NODES];
    __shared__ int lsrc[CSR_CAP];
    int b = blockIdx.x;
    int node0 = b << BKT_SHIFT;
    int p0 = bstart[b], p1 = bstart[b + 1];
    int cntb = p1 - p0;
    int tid = threadIdx.x;
    if (tid < BKT_NODES) { cnt[tid] = 0; cur[tid] = 0; }
    __syncthreads();
    for (int i = p0 + tid; i < p1; i += 256)
        atomicAdd(&cnt[pair_buf[i].y & (BKT_NODES - 1)], 1);
    __syncthreads();
    if (tid < BKT_NODES) incl[tid] = cnt[tid];
    __syncthreads();
    for (int off = 1; off < BKT_NODES; off <<= 1) {
        int v = 0;
        if (tid < BKT_NODES && tid >= off) v = incl[tid - off];
        __syncthreads();
        if (tid < BKT_NODES) incl[tid] += v;
        __syncthreads();
    }
    if (tid < BKT_NODES) {
        int n = node0 + tid;
        if (n < N) row_start[n] = p0 + incl[tid] - cnt[tid];   // exclusive
    }
    if (b == 0 && tid == 0) row_start[N] = E;
    bool fit = (cntb <= CSR_CAP);
    __syncthreads();
    for (int i = p0 + tid; i < p1; i += 256) {
        int2 pr = pair_buf[i];
        int ln = pr.y & (BKT_NODES - 1);
        int slot = incl[ln] - cnt[ln] + atomicAdd(&cur[ln], 1);
        if (fit) lsrc[slot] = pr.x;
        else     esrc[p0 + slot] = pr.x;    // overflow fallback (never for this E/N)
    }
    __syncthreads();
    if (fit)
        for (int i = tid; i < cntb; i += 256) esrc[p0 + i] = lsrc[i];
}

// ---------- fused attention v8: MFMA QK^T (fp8), 16 edges/group ----------
// A-frag: lane holds 8B of k8[src[edge=lane&15]] at dims 32j+quad*8 (gather bytes
// unchanged vs v6). B-frag: q8 bytes 32j+quad*8, broadcast over the 16 cols.
// D: lane gets dots of edges quad*4+r in regs -> p is register-local for PV,
// eliminating the per-edge 4-step shuffle reduce (16 shfl/16edges -> 0) and the
// k dequant VALU chain.
__global__ __launch_bounds__(256) void attn_kernel(
    const uint8_t* __restrict__ q8, const uint8_t* __restrict__ k8,
    const uint16_t* __restrict__ v,
    const int* __restrict__ row_start, const int* __restrict__ esrc,
    const float* __restrict__ curv,
    uint16_t* __restrict__ t_out,    // mode 0: h as fp16 (next layer tangent)
    float* __restrict__ x_out,       // mode 1: exp_map(h) fp32 -> d_out
    int N, int mode) {
    int wave = threadIdx.x >> 6, lane = threadIdx.x & 63;
    int sub = lane & 15, quad = lane >> 4;
    int n = blockIdx.x * 4 + wave;
    if (n >= N) return;
    int s0 = row_start[n], s1 = row_start[n + 1];
    const uint8_t* qrow = q8 + (size_t)n * DIM;
    uint2 qb0 = *(const uint2*)(qrow + quad * 8);
    uint2 qb1 = *(const uint2*)(qrow + 32 + quad * 8);
    uint2 qb2 = *(const uint2*)(qrow + 64 + quad * 8);
    uint2 qb3 = *(const uint2*)(qrow + 96 + quad * 8);
    const float K2 = 0.12751744154470514f;   // log2(e)/sqrt(128): one v_exp_f32, no ln2 mul
    float l = 0.0f;
    half2_t h2[4] = {};
    for (int s = s0; s < s1; s += 64) {
        // one coalesced load covers up to 64 edges' src indices (deg>=1 so s1-1>=s0)
        int idx = s + lane;
        int sidx_all = __builtin_nontemporal_load(esrc + (idx < s1 ? idx : s1 - 1));
        int ng = min(4, ((s1 - s) + 15) >> 4);         // 16-edge groups this chunk
        for (int g = 0; g < ng; g++) {
            int kb = g * 16;
            // ---- load phase ----
            int ksrc = __shfl(sidx_all, kb + sub);      // src of edge kb+sub
            size_t ka = (size_t)ksrc * DIM + quad * 8;
            uint2 a0 = *(const uint2*)(k8 + ka);
            uint2 a1 = *(const uint2*)(k8 + ka + 32);
            uint2 a2 = *(const uint2*)(k8 + ka + 64);
            uint2 a3 = *(const uint2*)(k8 + ka + 96);
            uint4 vu[4];
            #pragma unroll
            for (int r = 0; r < 4; r++) {
                int vsrc = __shfl(sidx_all, kb + quad * 4 + r);
                vu[r] = *(const uint4*)(v + (size_t)vsrc * DIM + sub * 8);
            }
            // ---- 16 dots in 4 fp8 MFMAs ----
            f32x4 d = {};
            d = mfma_fp8(a0, qb0, d);
            d = mfma_fp8(a1, qb1, d);
            d = mfma_fp8(a2, qb2, d);
            d = mfma_fp8(a3, qb3, d);
            // ---- softmax-weight + PV (p register-local: edge = kb+quad*4+r) ----
            #pragma unroll
            for (int r = 0; r < 4; r++) {
                int e = s + kb + quad * 4 + r;
                float p = (e < s1) ? __builtin_amdgcn_exp2f(d[r] * K2) : 0.0f;
                l += p;
                _Float16 pf = (_Float16)p;       // RNE
                half2_t ph = {pf, pf};
                #pragma unroll
                for (int i = 0; i < 4; i++) {
                    half2_t vh = __builtin_bit_cast(half2_t, ((const uint32_t*)&vu[r])[i]);
                    h2[i] += ph * vh;            // v_pk_fma_f16
                }
            }
        }
    }
    // reduce across the 4 quads (lanes within a quad hold identical l/p state)
    #pragma unroll
    for (int off = 16; off <= 32; off <<= 1) {
        l += __shfl_xor(l, off);
        #pragma unroll
        for (int i = 0; i < 4; i++) {
            uint32_t hw = __builtin_bit_cast(uint32_t, h2[i]);
            hw = __shfl_xor(hw, off);
            h2[i] += __builtin_bit_cast(half2_t, hw);
        }
    }
    float rl = 1.0f / l;
    if (mode == 0) {
        if (quad == 0) {
            _Float16 rlh = (_Float16)rl;
            half2_t rl2 = {rlh, rlh};
            uint4 pk;
            pk.x = __builtin_bit_cast(uint32_t, h2[0] * rl2);
            pk.y = __builtin_bit_cast(uint32_t, h2[1] * rl2);
            pk.z = __builtin_bit_cast(uint32_t, h2[2] * rl2);
            pk.w = __builtin_bit_cast(uint32_t, h2[3] * rl2);
            *(uint4*)(t_out + (size_t)n * DIM + sub * 8) = pk;   // re-read by next gemm: keep cached
        }
    } else {
        float h[8];
        #pragma unroll
        for (int i = 0; i < 4; i++) {
            h[2 * i]     = (float)h2[i].x * rl;
            h[2 * i + 1] = (float)h2[i].y * rl;
        }
        float ss = 0.0f;
        #pragma unroll
        for (int j = 0; j < 8; j++) ss += h[j] * h[j];
        #pragma unroll
        for (int off = 8; off >= 1; off >>= 1) ss += __shfl_xor(ss, off);
        float c = curv[0];
        float sc = sqrtf(c);
        float nh = sqrtf(ss);
        float f = (nh > 1e-30f) ? tanhf(sc * nh * 0.5f) / (sc * nh) : 0.5f;
        if (quad == 0) {
            f32x4 o0 = {f * h[0], f * h[1], f * h[2], f * h[3]};
            f32x4 o1 = {f * h[4], f * h[5], f * h[6], f * h[7]};
            __builtin_nontemporal_store(o0, (f32x4*)(x_out + (size_t)n * DIM + sub * 8));
            __builtin_nontemporal_store(o1, (f32x4*)(x_out + (size_t)n * DIM + sub * 8 + 4));
        }
    }
}

// ---------- host ----------
extern "C" void kernel_launch(void* const* d_in, const int* in_sizes, int n_in,
                              void* d_out, int out_size, void* d_ws, size_t ws_size,
                              hipStream_t stream) {
    const float* emb  = (const float*)d_in[0];
    const float* Wq   = (const float*)d_in[1];
    const float* bq   = (const float*)d_in[2];
    const float* Wk   = (const float*)d_in[3];
    const float* bk   = (const float*)d_in[4];
    const float* Wv   = (const float*)d_in[5];
    const float* bv   = (const float*)d_in[6];
    const float* curv = (const float*)d_in[7];
    const int*   srcp = (const int*)d_in[8];
    const int*   dstp = (const int*)d_in[9];

    const int N = in_sizes[0] / DIM;
    const int L = in_sizes[2] / DIM;
    const int E = in_sizes[8];

    uint8_t* ws = (uint8_t*)d_ws;
    size_t off = 0;
    auto carve = [&](size_t bytes) { size_t o = off; off = (off + bytes + 255) & ~(size_t)255; return o; };
    uint16_t* t_buf   = (uint16_t*)(ws + carve((size_t)N * DIM * 2));
    uint8_t*  q8b     = (uint8_t*)(ws + carve((size_t)N * DIM));
    uint16_t* vb      = (uint16_t*)(ws + carve((size_t)N * DIM * 2));
    uint8_t*  k8b     = (uint8_t*)(ws + carve((size_t)N * DIM));
    uint16_t* w_h     = (uint16_t*)(ws + carve((size_t)L * 3 * DIM * DIM * 2));
    int* row_start    = (int*)(ws + carve((size_t)(N + 1) * 4));
    int* bucket_cnt   = (int*)(ws + carve((MAX_BKT + 1) * 4));   // +1: done counter
    int* bstart       = (int*)(ws + carve((MAX_BKT + 1) * 4));
    int* bcursor      = (int*)(ws + carve(MAX_BKT * 4));
    int* esrc         = (int*)(ws + carve((size_t)E * 4));
    (void)ws_size;
    int* done_cnt = bucket_cnt + MAX_BKT;
    // pair_buf lives in d_out scratch: d_out (N*128*4 B >= E*8 B) is only written by
    // the FINAL attn dispatch; csr consumes pair_buf before that.
    int2* pair_buf = (int2*)d_out;

    const int nbuckets = (N + BKT_NODES - 1) >> BKT_SHIFT;   // N<=131072
    const int nbin = (E + BIN_TILE - 1) / BIN_TILE;
    const int wtotal = L * 3 * DIM * DIM;
    const int ntiles = (N + 255) / 256;

    // --- prep: histogram(+scan) + weight convert + tangent (one role-split dispatch) ---
    (void)hipMemsetAsync(bucket_cnt, 0, (size_t)(MAX_BKT + 1) * 4, stream);
    int prep_grid = nbin + NW_BLK + (N + 31) / 32;
    prep_kernel<<<prep_grid, 256, 0, stream>>>(dstp, bucket_cnt, done_cnt, bstart, bcursor,
                                               E, nbuckets, nbin,
                                               Wq, Wk, Wv, w_h, wtotal,
                                               emb, t_buf, curv, N);
    // --- combo: bin + layer-0 gemm in one dispatch (independent roles) ---
    bin_gemm_kernel<<<nbin + 3 * ntiles, 256, 0, stream>>>(
        srcp, dstp, bcursor, pair_buf, E, nbuckets, nbin,
        t_buf, w_h, bq, bk, bv, q8b, k8b, vb, N, ntiles);
    csr_kernel<<<nbuckets, 256, 0, stream>>>(pair_buf, bstart, row_start, esrc, N, E);

    // layer 0 attention
    attn_kernel<<<(N + 3) / 4, 256, 0, stream>>>(
        q8b, k8b, vb, row_start, esrc, curv, t_buf, (float*)d_out, N, (L == 1) ? 1 : 0);
    // remaining layers
    dim3 ggrid(ntiles, 3);
    for (int l = 1; l < L; l++) {
        qkv_gemm_kernel<<<ggrid, 256, 0, stream>>>(
            t_buf, w_h + (size_t)l * 3 * DIM * DIM,
            bq + (size_t)l * DIM, bk + (size_t)l * DIM, bv + (size_t)l * DIM,
            q8b, k8b, vb, N);
        int mode = (l == L - 1) ? 1 : 0;
        // log_map(exp_map(h)) == h exactly -> intermediate layer writes h as next tangent
        attn_kernel<<<(N + 3) / 4, 256, 0, stream>>>(
            q8b, k8b, vb, row_start, esrc, curv, t_buf, (float*)d_out, N, mode);
    }
}

// Round 13
// 442.758 us; speedup vs baseline: 1.0445x; 1.0445x over previous
//
#include <hip/hip_runtime.h>
#include <hip/hip_bf16.h>
#include <stdint.h>

// ---------- types / helpers ----------
typedef __attribute__((ext_vector_type(8))) short short8;   // 8 fp16 (MFMA A/B frag)
typedef __attribute__((ext_vector_type(4))) float f32x4;    // MFMA C/D frag
typedef __attribute__((ext_vector_type(2))) float f32x2;
typedef __attribute__((ext_vector_type(4))) unsigned int u32x4;  // nontemporal-capable 16B
typedef __attribute__((ext_vector_type(2))) unsigned int u32x2;  // nontemporal-capable 8B
typedef __attribute__((ext_vector_type(2))) _Float16 half2_t;

__device__ __forceinline__ uint32_t pack2(float a, float b) {
    auto r = __builtin_amdgcn_cvt_pkrtz(a, b);              // v_cvt_pkrtz_f16_f32
    return __builtin_bit_cast(uint32_t, r);
}
__device__ __forceinline__ uint16_t f2h(float x) {
    auto r = __builtin_amdgcn_cvt_pkrtz(x, 0.0f);
    return (uint16_t)(__builtin_bit_cast(uint32_t, r) & 0xffffu);
}

// ---- wave run-aggregation for LDS atomics (sorted dst -> same-address RMW fix) ----
// All 64 lanes must execute these. Invalid lanes pass b = -1 (contiguous at wave tail).
__device__ __forceinline__ void agg_hist_add(int b, int lane, int* lcnt) {
    int prev = __shfl_up(b, 1);
    bool head = (lane == 0) || (b != prev);
    unsigned long long heads = __ballot(head);
    unsigned long long mask_le = ((1ull << lane) << 1) - 1ull;   // bits 0..lane (lane=63 -> ~0)
    unsigned long long g = heads & ~mask_le;                     // heads strictly after lane
    int nexthead = g ? (int)__builtin_ctzll(g) : 64;
    if (head && b >= 0) atomicAdd(&lcnt[b], nexthead - lane);    // one RMW per run
}
__device__ __forceinline__ int agg_slot(int b, int lane, int* cnt) {
    int prev = __shfl_up(b, 1);
    bool head = (lane == 0) || (b != prev);
    unsigned long long heads = __ballot(head);
    unsigned long long mask_le = ((1ull << lane) << 1) - 1ull;
    unsigned long long m = heads & mask_le;                      // nonzero: lane0 is a head
    int myhead = 63 - (int)__builtin_clzll(m);
    unsigned long long g = heads & ~mask_le;
    int nexthead = g ? (int)__builtin_ctzll(g) : 64;
    int base = 0;
    if (lane == myhead && b >= 0) base = atomicAdd(&cnt[b], nexthead - lane);
    base = __shfl(base, myhead);
    return base + (lane - myhead);   // caller uses only on valid lanes
}

#define DIM 128
// CSR bucket sort: 128 nodes per bucket (bucket = dst >> 7). Works for N <= 131072.
#define BKT_SHIFT 7
#define BKT_NODES 128
#define MAX_BKT 1024
#define BIN_TILE 8192   // 196 blocks at E=1.6M: TLP for the latency-bound hist/scatter
#define CSR_CAP 3072   // max edges per bucket staged in LDS (mean ~2046, std ~45)
#define LDS_W_STRIDE 136   // 128 + 8 halves: breaks 16-way bank conflict on ds_read_b128
#define NW_BLK 16      // weight-convert role blocks

// ---------- prep: bucket histogram (+inline last-block scan) + weight convert + tangent ----------
__global__ __launch_bounds__(256) void prep_kernel(
    const int* __restrict__ dst, int* __restrict__ bucket_cnt, int* __restrict__ done_cnt,
    int* __restrict__ bstart, int* __restrict__ bcursor,
    int E, int nbuckets, int nbin,
    const float* __restrict__ Wq, const float* __restrict__ Wk, const float* __restrict__ Wv,
    uint16_t* __restrict__ w_h, int wtotal,
    const float* __restrict__ x, uint16_t* __restrict__ t, const float* __restrict__ curv,
    int N) {
    __shared__ int lcnt[MAX_BKT];
    __shared__ int is_last;
    int bx = blockIdx.x;
    int tid = threadIdx.x;
    if (bx < nbin) {
        // --- bucket histogram role (wave-aggregated LDS atomics) ---
        for (int i = tid; i < nbuckets; i += 256) lcnt[i] = 0;
        __syncthreads();
        int base = bx * BIN_TILE;
        int end = min(base + BIN_TILE, E);
        int lane = tid & 63;
        for (int e0 = base; e0 < end; e0 += 256) {
            int e = e0 + tid;
            int b = (e < end) ? (dst[e] >> BKT_SHIFT) : -1;
            agg_hist_add(b, lane, lcnt);
        }
        __syncthreads();
        for (int i = tid; i < nbuckets; i += 256)
            if (lcnt[i]) atomicAdd(&bucket_cnt[i], lcnt[i]);
        // --- last histogram block performs the exclusive scan inline (was bscan_kernel) ---
        if (tid == 0) {
            __threadfence();                               // release our bucket_cnt adds
            int d = atomicAdd(done_cnt, 1);
            is_last = (d == nbin - 1);
        }
        __syncthreads();
        if (is_last) {
            __threadfence();                               // acquire other blocks' adds
            int v4[4];
            #pragma unroll
            for (int c = 0; c < 4; c++) {
                int idx = c * 256 + tid;
                v4[c] = (idx < nbuckets)
                    ? __hip_atomic_load(&bucket_cnt[idx], __ATOMIC_RELAXED, __HIP_MEMORY_SCOPE_AGENT)
                    : 0;
            }
            int run = 0;
            #pragma unroll
            for (int c = 0; c < 4; c++) {
                lcnt[tid] = v4[c]; __syncthreads();
                for (int off = 1; off < 256; off <<= 1) {
                    int tv = (tid >= off) ? lcnt[tid - off] : 0;
                    __syncthreads();
                    lcnt[tid] += tv;
                    __syncthreads();
                }
                int ex = run + lcnt[tid] - v4[c];
                int idx = c * 256 + tid;
                if (idx < nbuckets) { bstart[idx] = ex; bcursor[idx] = ex; }
                run += lcnt[255];
                __syncthreads();
            }
            if (tid == 0) bstart[nbuckets] = E;
        }
    } else if (bx < nbin + NW_BLK) {
        // --- weight conversion role: [l][mat][out_col][k] fp32 -> fp16 ---
        int per_l = 3 * DIM * DIM;
        for (int i = (bx - nbin) * 256 + tid; i < wtotal; i += 256 * NW_BLK) {
            int l = i / per_l;
            int rem = i % per_l;
            int mat = rem / (DIM * DIM);
            int idx = rem % (DIM * DIM);
            const float* s = (mat == 0) ? Wq : (mat == 1) ? Wk : Wv;
            w_h[i] = f2h(s[l * DIM * DIM + idx]);
        }
    } else {
        // --- tangent role: 32 nodes/block, 8 lanes/node, 64B per lane ---
        // t = (2/sc)*atanh(sc*||x||)*x/||x||; atanh via one v_log_f32.
        int n = (bx - nbin - NW_BLK) * 32 + (tid >> 3);
        if (n >= N) return;
        int ln8 = tid & 7;
        const float4* xp = (const float4*)(x + (size_t)n * DIM) + ln8 * 4;
        float4 a0 = xp[0], a1 = xp[1], a2 = xp[2], a3 = xp[3];
        float ss = a0.x * a0.x + a0.y * a0.y + a0.z * a0.z + a0.w * a0.w
                 + a1.x * a1.x + a1.y * a1.y + a1.z * a1.z + a1.w * a1.w
                 + a2.x * a2.x + a2.y * a2.y + a2.z * a2.z + a2.w * a2.w
                 + a3.x * a3.x + a3.y * a3.y + a3.z * a3.z + a3.w * a3.w;
        #pragma unroll
        for (int off = 4; off >= 1; off >>= 1) ss += __shfl_xor(ss, off);
        float c = curv[0];
        float sc = sqrtf(c);
        float r = sqrtf(ss);
        float z = sc * r;
        float f = (r > 1e-30f) ? __logf((1.0f + z) / (1.0f - z)) / (sc * r) : 2.0f;
        uint4 o0, o1;
        o0.x = pack2(f * a0.x, f * a0.y); o0.y = pack2(f * a0.z, f * a0.w);
        o0.z = pack2(f * a1.x, f * a1.y); o0.w = pack2(f * a1.z, f * a1.w);
        o1.x = pack2(f * a2.x, f * a2.y); o1.y = pack2(f * a2.z, f * a2.w);
        o1.z = pack2(f * a3.x, f * a3.y); o1.w = pack2(f * a3.z, f * a3.w);
        uint4* tp = (uint4*)(t + (size_t)n * DIM) + ln8 * 2;
        tp[0] = o0; tp[1] = o1;
    }
}

// ---------- shared gemm body: 2-pass col-tile split (acc[4][4] = 64 VGPR, was 128) ----------
// Round-11 counters: VGPR 140 -> 9.5% occupancy -> t-load latency unhidden. Two passes
// of 4 col-tiles halve the accumulator; b[] reloads in pass 2 are L1/L2 hits.
// mat 0: q fp8 e4m3 + bias. mat 1: k fp8 + bias. mat 2: v fp16 + bias.
__device__ __forceinline__ void qkv_gemm_body(
    const uint16_t* __restrict__ t, const uint16_t* __restrict__ w,
    const float* __restrict__ bq, const float* __restrict__ bk, const float* __restrict__ bv,
    uint8_t* __restrict__ q8out, uint8_t* __restrict__ k8out, uint16_t* __restrict__ vout,
    int N, int mat, int tile, uint16_t* lw) {
    const uint16_t* wm = w + (size_t)mat * DIM * DIM;
    // stage W: each thread copies half a row (64 halves = 8 x uint4)
    {
        int r = threadIdx.x >> 1, hf = (threadIdx.x & 1) * 64;
        const uint4* srcp = (const uint4*)(wm + r * DIM + hf);
        uint4* dstp = (uint4*)(lw + r * LDS_W_STRIDE + hf);
        #pragma unroll
        for (int i = 0; i < 8; i++) dstp[i] = srcp[i];
    }
    __syncthreads();
    int wave = threadIdx.x >> 6, lane = threadIdx.x & 63;
    int sub = lane & 15, quad = lane >> 4;
    int node0 = tile * 256 + wave * 64;
    const float* bias = (mat == 0) ? bq : (mat == 1) ? bk : bv;
    for (int half = 0; half < 2; half++) {      // NOT unrolled: keeps one half's state live
        f32x4 acc[4][4] = {};
        #pragma unroll
        for (int k0 = 0; k0 < DIM; k0 += 32) {
            short8 b[4];
            #pragma unroll
            for (int g = 0; g < 4; g++) {
                int node = node0 + g * 16 + sub;
                int nodec = (node < N) ? node : (N - 1);
                b[g] = *(const short8*)(t + (size_t)nodec * DIM + k0 + quad * 8);
            }
            #pragma unroll
            for (int tl = 0; tl < 4; tl++) {
                short8 a = *(const short8*)(lw + ((half * 4 + tl) * 16 + sub) * LDS_W_STRIDE + k0 + quad * 8);
                #pragma unroll
                for (int g = 0; g < 4; g++)
                    acc[tl][g] = __builtin_amdgcn_mfma_f32_16x16x32_f16(a, b[g], acc[tl][g], 0, 0, 0);
            }
        }
        #pragma unroll
        for (int g = 0; g < 4; g++) {
            int node = node0 + g * 16 + sub;
            if (node >= N) continue;
            #pragma unroll
            for (int tl = 0; tl < 4; tl++) {
                int tlg = half * 4 + tl;
                float4 bs = *(const float4*)(bias + tlg * 16 + quad * 4);
                if (mat != 2) {
                    uint8_t* outp = (mat == 0) ? q8out : k8out;
                    int pk = 0;
                    pk = __builtin_amdgcn_cvt_pk_fp8_f32(acc[tl][g][0] + bs.x, acc[tl][g][1] + bs.y, pk, false);
                    pk = __builtin_amdgcn_cvt_pk_fp8_f32(acc[tl][g][2] + bs.z, acc[tl][g][3] + bs.w, pk, true);
                    *(uint32_t*)(outp + (size_t)node * DIM + tlg * 16 + quad * 4) = (uint32_t)pk;
                } else {
                    uint2 pk;
                    pk.x = pack2(acc[tl][g][0] + bs.x, acc[tl][g][1] + bs.y);
                    pk.y = pack2(acc[tl][g][2] + bs.z, acc[tl][g][3] + bs.w);
                    *(uint2*)(vout + (size_t)node * DIM + tlg * 16 + quad * 4) = pk;
                }
            }
        }
    }
}

// ---------- combo: two-phase bin (role) + layer-0 QKV gemm (role), one dispatch ----------
__global__ __launch_bounds__(256) void bin_gemm_kernel(
    const int* __restrict__ src, const int* __restrict__ dst,
    int* __restrict__ bcursor, int2* __restrict__ pair_buf, int E, int nbuckets, int nbin,
    const uint16_t* __restrict__ t, const uint16_t* __restrict__ w,
    const float* __restrict__ bq, const float* __restrict__ bk, const float* __restrict__ bv,
    uint8_t* __restrict__ q8out, uint8_t* __restrict__ k8out, uint16_t* __restrict__ vout,
    int N, int ntiles) {
    __shared__ uint16_t lw[DIM * LDS_W_STRIDE];
    int bx = blockIdx.x;
    if (bx < nbin) {
        // --- bin role: two-phase LDS scatter (round-9 proven form) ---
        int* lcnt = (int*)lw;                        // reuse gemm LDS
        int* lbase = lcnt + MAX_BKT;
        int lane = threadIdx.x & 63;
        for (int i = threadIdx.x; i < nbuckets; i += 256) lcnt[i] = 0;
        __syncthreads();
        int base = bx * BIN_TILE;
        int end = min(base + BIN_TILE, E);
        for (int e0 = base; e0 < end; e0 += 256) {
            int e = e0 + threadIdx.x;
            int b = (e < end) ? (dst[e] >> BKT_SHIFT) : -1;
            agg_hist_add(b, lane, lcnt);
        }
        __syncthreads();
        for (int i = threadIdx.x; i < nbuckets; i += 256) {
            int c = lcnt[i];
            lbase[i] = c ? atomicAdd(&bcursor[i], c) : 0;
        }
        __syncthreads();
        for (int i = threadIdx.x; i < nbuckets; i += 256) lcnt[i] = 0;   // reuse as cursor
        __syncthreads();
        for (int e0 = base; e0 < end; e0 += 256) {
            int e = e0 + threadIdx.x;
            bool valid = (e < end);
            int d = valid ? dst[e] : 0;
            int b = valid ? (d >> BKT_SHIFT) : -1;
            int slot = agg_slot(b, lane, lcnt);
            if (valid) pair_buf[(size_t)lbase[b] + slot] = make_int2(src[e], d);
        }
    } else {
        int id = bx - nbin;
        int mat = id / ntiles, tile = id % ntiles;   // all tiles of mat 0 first: t L3-reuse
        qkv_gemm_body(t, w, bq, bk, bv, q8out, k8out, vout, N, mat, tile, lw);
    }
}

// ---------- standalone QKV gemm (layers >= 1) ----------
__global__ __launch_bounds__(256) void qkv_gemm_kernel(
    const uint16_t* __restrict__ t, const uint16_t* __restrict__ w,
    const float* __restrict__ bq, const float* __restrict__ bk, const float* __restrict__ bv,
    uint8_t* __restrict__ q8out, uint8_t* __restrict__ k8out, uint16_t* __restrict__ vout,
    int N) {
    __shared__ uint16_t lw[DIM * LDS_W_STRIDE];
    qkv_gemm_body(t, w, bq, bk, bv, q8out, k8out, vout, N, blockIdx.y, blockIdx.x, lw);
}

// ---------- CSR build: per-bucket local sort in LDS -> row_start + esrc ----------
__global__ __launch_bounds__(256) void csr_kernel(const int2* __restrict__ pair_buf,
                                                  const int* __restrict__ bstart,
                                                  int* __restrict__ row_start,
                                                  int* __restrict__ esrc,
                                                  int N, int E) {
    __shared__ int cnt[BKT_NODES], incl[BKT_NODES], cur[BKT_NODES];
    __shared__ int lsrc[CSR_CAP];
    int b = blockIdx.x;
    int node0 = b << BKT_SHIFT;
    int p0 = bstart[b], p1 = bstart[b + 1];
    int cntb = p1 - p0;
    int tid = threadIdx.x;
    if (tid < BKT_NODES) { cnt[tid] = 0; cur[tid] = 0; }
    __syncthreads();
    for (int i = p0 + tid; i < p1; i += 256)
        atomicAdd(&cnt[pair_buf[i].y & (BKT_NODES - 1)], 1);
    __syncthreads();
    if (tid < BKT_NODES) incl[tid] = cnt[tid];
    __syncthreads();
    for (int off = 1; off < BKT_NODES; off <<= 1) {
        int v = 0;
        if (tid < BKT_NODES && tid >= off) v = incl[tid - off];
        __syncthreads();
        if (tid < BKT_NODES) incl[tid] += v;
        __syncthreads();
    }
    if (tid < BKT_NODES) {
        int n = node0 + tid;
        if (n < N) row_start[n] = p0 + incl[tid] - cnt[tid];   // exclusive
    }
    if (b == 0 && tid == 0) row_start[N] = E;
    bool fit = (cntb <= CSR_CAP);
    __syncthreads();
    for (int i = p0 + tid; i < p1; i += 256) {
        int2 pr = pair_buf[i];
        int ln = pr.y & (BKT_NODES - 1);
        int slot = incl[ln] - cnt[ln] + atomicAdd(&cur[ln], 1);
        if (fit) lsrc[slot] = pr.x;
        else     esrc[p0 + slot] = pr.x;    // overflow fallback (never for this E/N)
    }
    __syncthreads();
    if (fit)
        for (int i = tid; i < cntb; i += 256) esrc[p0 + i] = lsrc[i];
}

// ---------- fused attention v9: v6 scalar-dot structure (proven 91us) with q in fp8 ----------
// Round-12's MFMA QK^T regressed (latency chain deepened); revert the dot to the
// per-quarter-wave scalar form. q stays fp8 (round-12 proved absmax unchanged):
// dequant once in preamble (4 cvt_pk).
__global__ __launch_bounds__(256) void attn_kernel(
    const uint8_t* __restrict__ q8, const uint8_t* __restrict__ k8,
    const uint16_t* __restrict__ v,
    const int* __restrict__ row_start, const int* __restrict__ esrc,
    const float* __restrict__ curv,
    uint16_t* __restrict__ t_out,    // mode 0: h as fp16 (next layer tangent)
    float* __restrict__ x_out,       // mode 1: exp_map(h) fp32 -> d_out
    int N, int mode) {
    int wave = threadIdx.x >> 6, lane = threadIdx.x & 63;
    int sub = lane & 15, quad = lane >> 4;
    int n = blockIdx.x * 4 + wave;
    if (n >= N) return;
    int s0 = row_start[n], s1 = row_start[n + 1];
    u32x2 qv = __builtin_nontemporal_load((const u32x2*)(q8 + (size_t)n * DIM + sub * 8));
    f32x2 qf2[4];
    qf2[0] = __builtin_amdgcn_cvt_pk_f32_fp8(qv[0], false);
    qf2[1] = __builtin_amdgcn_cvt_pk_f32_fp8(qv[0], true);
    qf2[2] = __builtin_amdgcn_cvt_pk_f32_fp8(qv[1], false);
    qf2[3] = __builtin_amdgcn_cvt_pk_f32_fp8(qv[1], true);
    const float K2 = 0.12751744154470514f;   // log2(e)/sqrt(128): one v_exp_f32, no ln2 mul
    float l = 0.0f;
    half2_t h2[4] = {};
    for (int s = s0; s < s1; s += 64) {
        // one coalesced load covers up to 64 edges' src indices (deg>=1 so s1-1>=s0)
        int idx = s + lane;
        int sidx_all = __builtin_nontemporal_load(esrc + (idx < s1 ? idx : s1 - 1));
        int m = min(16, ((s1 - s) + 3) >> 2);          // 4-edge iterations this chunk
        for (int it0 = 0; it0 < m; it0 += 4) {
            uint2 ku[4]; uint4 vu[4];
            // ---- load phase: issue all 8 gathers for 16 edges ----
            #pragma unroll
            for (int u = 0; u < 4; u++) {
                int sx = __shfl(sidx_all, (it0 + u) * 4 + quad);   // ds_bpermute, ~30cy
                int ko = sx * DIM + sub * 8;                        // shared k8/v element index
                ku[u] = *(const uint2*)(k8 + ko);
                vu[u] = *(const uint4*)(v + ko);
            }
            // ---- compute phase ----
            #pragma unroll
            for (int u = 0; u < 4; u++) {
                int e = s + (it0 + u) * 4 + quad;
                bool valid = (e < s1);
                f32x2 d0 = __builtin_amdgcn_cvt_pk_f32_fp8(ku[u].x, false);
                f32x2 d1 = __builtin_amdgcn_cvt_pk_f32_fp8(ku[u].x, true);
                f32x2 d2 = __builtin_amdgcn_cvt_pk_f32_fp8(ku[u].y, false);
                f32x2 d3 = __builtin_amdgcn_cvt_pk_f32_fp8(ku[u].y, true);
                f32x2 acc2 = qf2[0] * d0;        // fp-contract=fast -> v_pk_fma_f32 chain
                acc2 += qf2[1] * d1;
                acc2 += qf2[2] * d2;
                acc2 += qf2[3] * d3;
                float dot = acc2[0] + acc2[1];
                #pragma unroll
                for (int off = 8; off >= 1; off >>= 1) dot += __shfl_xor(dot, off);
                float p = valid ? __builtin_amdgcn_exp2f(dot * K2) : 0.0f;
                l += p;
                _Float16 pf = (_Float16)p;       // RNE
                half2_t ph = {pf, pf};
                #pragma unroll
                for (int i = 0; i < 4; i++) {
                    half2_t vh = __builtin_bit_cast(half2_t, ((const uint32_t*)&vu[u])[i]);
                    h2[i] += ph * vh;            // v_pk_fma_f16
                }
            }
        }
    }
    #pragma unroll
    for (int off = 16; off <= 32; off <<= 1) {
        l += __shfl_xor(l, off);
        #pragma unroll
        for (int i = 0; i < 4; i++) {
            uint32_t hw = __builtin_bit_cast(uint32_t, h2[i]);
            hw = __shfl_xor(hw, off);
            h2[i] += __builtin_bit_cast(half2_t, hw);
        }
    }
    float rl = 1.0f / l;
    if (mode == 0) {
        if (quad == 0) {
            _Float16 rlh = (_Float16)rl;
            half2_t rl2 = {rlh, rlh};
            uint4 pk;
            pk.x = __builtin_bit_cast(uint32_t, h2[0] * rl2);
            pk.y = __builtin_bit_cast(uint32_t, h2[1] * rl2);
            pk.z = __builtin_bit_cast(uint32_t, h2[2] * rl2);
            pk.w = __builtin_bit_cast(uint32_t, h2[3] * rl2);
            *(uint4*)(t_out + (size_t)n * DIM + sub * 8) = pk;   // re-read by next gemm: keep cached
        }
    } else {
        float h[8];
        #pragma unroll
        for (int i = 0; i < 4; i++) {
            h[2 * i]     = (float)h2[i].x * rl;
            h[2 * i + 1] = (float)h2[i].y * rl;
        }
        float ss = 0.0f;
        #pragma unroll
        for (int j = 0; j < 8; j++) ss += h[j] * h[j];
        #pragma unroll
        for (int off = 8; off >= 1; off >>= 1) ss += __shfl_xor(ss, off);
        float c = curv[0];
        float sc = sqrtf(c);
        float nh = sqrtf(ss);
        float f = (nh > 1e-30f) ? tanhf(sc * nh * 0.5f) / (sc * nh) : 0.5f;
        if (quad == 0) {
            f32x4 o0 = {f * h[0], f * h[1], f * h[2], f * h[3]};
            f32x4 o1 = {f * h[4], f * h[5], f * h[6], f * h[7]};
            __builtin_nontemporal_store(o0, (f32x4*)(x_out + (size_t)n * DIM + sub * 8));
            __builtin_nontemporal_store(o1, (f32x4*)(x_out + (size_t)n * DIM + sub * 8 + 4));
        }
    }
}

// ---------- host ----------
extern "C" void kernel_launch(void* const* d_in, const int* in_sizes, int n_in,
                              void* d_out, int out_size, void* d_ws, size_t ws_size,
                              hipStream_t stream) {
    const float* emb  = (const float*)d_in[0];
    const float* Wq   = (const float*)d_in[1];
    const float* bq   = (const float*)d_in[2];
    const float* Wk   = (const float*)d_in[3];
    const float* bk   = (const float*)d_in[4];
    const float* Wv   = (const float*)d_in[5];
    const float* bv   = (const float*)d_in[6];
    const float* curv = (const float*)d_in[7];
    const int*   srcp = (const int*)d_in[8];
    const int*   dstp = (const int*)d_in[9];

    const int N = in_sizes[0] / DIM;
    const int L = in_sizes[2] / DIM;
    const int E = in_sizes[8];

    uint8_t* ws = (uint8_t*)d_ws;
    size_t off = 0;
    auto carve = [&](size_t bytes) { size_t o = off; off = (off + bytes + 255) & ~(size_t)255; return o; };
    uint16_t* t_buf   = (uint16_t*)(ws + carve((size_t)N * DIM * 2));
    uint8_t*  q8b     = (uint8_t*)(ws + carve((size_t)N * DIM));
    uint16_t* vb      = (uint16_t*)(ws + carve((size_t)N * DIM * 2));
    uint8_t*  k8b     = (uint8_t*)(ws + carve((size_t)N * DIM));
    uint16_t* w_h     = (uint16_t*)(ws + carve((size_t)L * 3 * DIM * DIM * 2));
    int* row_start    = (int*)(ws + carve((size_t)(N + 1) * 4));
    int* bucket_cnt   = (int*)(ws + carve((MAX_BKT + 1) * 4));   // +1: done counter
    int* bstart       = (int*)(ws + carve((MAX_BKT + 1) * 4));
    int* bcursor      = (int*)(ws + carve(MAX_BKT * 4));
    int* esrc         = (int*)(ws + carve((size_t)E * 4));
    (void)ws_size;
    int* done_cnt = bucket_cnt + MAX_BKT;
    // pair_buf lives in d_out scratch: d_out (N*128*4 B >= E*8 B) is only written by
    // the FINAL attn dispatch; csr consumes pair_buf before that.
    int2* pair_buf = (int2*)d_out;

    const int nbuckets = (N + BKT_NODES - 1) >> BKT_SHIFT;   // N<=131072
    const int nbin = (E + BIN_TILE - 1) / BIN_TILE;
    const int wtotal = L * 3 * DIM * DIM;
    const int ntiles = (N + 255) / 256;

    // --- prep: histogram(+scan) + weight convert + tangent (one role-split dispatch) ---
    (void)hipMemsetAsync(bucket_cnt, 0, (size_t)(MAX_BKT + 1) * 4, stream);
    int prep_grid = nbin + NW_BLK + (N + 31) / 32;
    prep_kernel<<<prep_grid, 256, 0, stream>>>(dstp, bucket_cnt, done_cnt, bstart, bcursor,
                                               E, nbuckets, nbin,
                                               Wq, Wk, Wv, w_h, wtotal,
                                               emb, t_buf, curv, N);
    // --- combo: bin + layer-0 gemm in one dispatch (independent roles) ---
    bin_gemm_kernel<<<nbin + 3 * ntiles, 256, 0, stream>>>(
        srcp, dstp, bcursor, pair_buf, E, nbuckets, nbin,
        t_buf, w_h, bq, bk, bv, q8b, k8b, vb, N, ntiles);
    csr_kernel<<<nbuckets, 256, 0, stream>>>(pair_buf, bstart, row_start, esrc, N, E);

    // layer 0 attention
    attn_kernel<<<(N + 3) / 4, 256, 0, stream>>>(
        q8b, k8b, vb, row_start, esrc, curv, t_buf, (float*)d_out, N, (L == 1) ? 1 : 0);
    // remaining layers
    dim3 ggrid(ntiles, 3);
    for (int l = 1; l < L; l++) {
        qkv_gemm_kernel<<<ggrid, 256, 0, stream>>>(
            t_buf, w_h + (size_t)l * 3 * DIM * DIM,
            bq + (size_t)l * DIM, bk + (size_t)l * DIM, bv + (size_t)l * DIM,
            q8b, k8b, vb, N);
        int mode = (l == L - 1) ? 1 : 0;
        // log_map(exp_map(h)) == h exactly -> intermediate layer writes h as next tangent
        attn_kernel<<<(N + 3) / 4, 256, 0, stream>>>(
            q8b, k8b, vb, row_start, esrc, curv, t_buf, (float*)d_out, N, mode);
    }
}